// Round 1
// baseline (118.315 us; speedup 1.0000x reference)
//
#include <hip/hip_runtime.h>
#include <math.h>

#define NUM_GRAPHS 512
#define D 128
#define HDIM 256

// ---------------------------------------------------------------------------
// Kernel A: one block per graph.
//   1) detect whether batch is int32 or int64 (reference casts to int64 but
//      harness contract says int32 -- handle both)
//   2) binary search [start,end) of this graph's nodes (batch is sorted)
//   3) segment-sum x rows (float4 coalesced) into LDS
//   4) per-graph MLP: relu(S@W1+b1) -> *count -> relu(@W2+b2) -> @Wc+bc
//      -> softplus(c)/(1+softplus(c)) -> cval[g]
// ---------------------------------------------------------------------------
__global__ __launch_bounds__(256) void graph_mlp(
    const float* __restrict__ x,
    const int*   __restrict__ batch32,
    const float* __restrict__ W1, const float* __restrict__ b1,
    const float* __restrict__ W2, const float* __restrict__ b2,
    const float* __restrict__ Wc, const float* __restrict__ bc,
    float* __restrict__ cval, int* __restrict__ flagOut, int N)
{
    const int g   = blockIdx.x;
    const int tid = threadIdx.x;

    __shared__ int    sIs64;
    __shared__ int    sStart, sEnd;
    __shared__ float4 part[256];     // 4 KB partial sums
    __shared__ float  sS[D];         // per-graph x-sum
    __shared__ float  sH[HDIM];      // scaled hidden layer 1
    __shared__ float  sRed[4];
    __shared__ int    sWave[4];

    // ---- int32 vs int64 detection (parallel scan of first words) ----
    {
        int cap = N < 8192 ? N : 8192;
        int local = 0x7fffffff;
        for (int i = tid; i < cap; i += 256) {
            if (batch32[i] != 0) { local = i; break; }
        }
        for (int off = 32; off > 0; off >>= 1)
            local = min(local, __shfl_down(local, off, 64));
        if ((tid & 63) == 0) sWave[tid >> 6] = local;
        __syncthreads();
        if (tid == 0) {
            int j = min(min(sWave[0], sWave[1]), min(sWave[2], sWave[3]));
            int is64 = 0;
            // int64 view of sorted small values: word after first nonzero
            // low-word is the (zero) high word. int32 sorted: it's nonzero.
            if (j != 0x7fffffff && j + 1 < N && batch32[j + 1] == 0) is64 = 1;
            sIs64 = is64;
            if (g == 0) *flagOut = is64;
        }
        __syncthreads();
    }
    const int is64 = sIs64;
    const long long* batch64 = (const long long*)batch32;

    // ---- binary search for [start, end) ----
    if (tid < 2) {
        int target = g + tid;           // lower_bound(target)
        int lo = 0, hi = N;
        while (lo < hi) {
            int m = (lo + hi) >> 1;
            long long v = is64 ? batch64[m] : (long long)batch32[m];
            if (v < (long long)target) lo = m + 1; else hi = m;
        }
        if (tid == 0) sStart = lo; else sEnd = lo;
    }
    __syncthreads();
    const int start = sStart, end = sEnd;
    const float cnt = (float)(end - start);

    // ---- segment sum: 8 row-groups x 32 float4 lanes ----
    const int r  = tid >> 5;     // 0..7
    const int c4 = tid & 31;     // 0..31 (covers dims 4*c4 .. 4*c4+3)
    float4 acc = make_float4(0.f, 0.f, 0.f, 0.f);
    const float4* x4 = (const float4*)x;          // row stride 32 float4
    for (int row = start + r; row < end; row += 8) {
        float4 v = x4[row * 32 + c4];
        acc.x += v.x; acc.y += v.y; acc.z += v.z; acc.w += v.w;
    }
    part[tid] = acc;
    __syncthreads();
    for (int s = 4; s >= 1; s >>= 1) {
        if (r < s) {
            float4 o = part[tid + s * 32];
            float4 m = part[tid];
            m.x += o.x; m.y += o.y; m.z += o.z; m.w += o.w;
            part[tid] = m;
        }
        __syncthreads();
    }
    if (tid < 32) {
        float4 v = part[tid];
        sS[tid * 4 + 0] = v.x;
        sS[tid * 4 + 1] = v.y;
        sS[tid * 4 + 2] = v.z;
        sS[tid * 4 + 3] = v.w;
    }
    __syncthreads();

    // ---- layer 1: thread t owns output column t ----
    float a1 = b1[tid];
    #pragma unroll 8
    for (int k = 0; k < D; ++k)
        a1 = fmaf(sS[k], W1[k * HDIM + tid], a1);
    sH[tid] = fmaxf(a1, 0.f) * cnt;   // agg over graph = count * H1
    __syncthreads();

    // ---- layer 2 + confidence head ----
    float a2 = b2[tid];
    #pragma unroll 8
    for (int k = 0; k < HDIM; ++k)
        a2 = fmaf(sH[k], W2[k * HDIM + tid], a2);
    float h2 = fmaxf(a2, 0.f);
    float v = h2 * Wc[tid];
    for (int off = 32; off > 0; off >>= 1)
        v += __shfl_down(v, off, 64);
    if ((tid & 63) == 0) sRed[tid >> 6] = v;
    __syncthreads();
    if (tid == 0) {
        float cc = sRed[0] + sRed[1] + sRed[2] + sRed[3] + bc[0];
        // softplus(c) = max(c,0) + log1p(exp(-|c|))  (JAX-stable form)
        float m  = fmaxf(cc, 0.f);
        float sp = m + log1pf(expf(-fabsf(cc)));
        cval[g] = sp / (1.f + sp);
    }
}

// ---------------------------------------------------------------------------
// Kernel B: broadcast per-graph scalar back to nodes.
// ---------------------------------------------------------------------------
__global__ __launch_bounds__(256) void scatter_out(
    const int* __restrict__ batch32, const int* __restrict__ flag,
    const float* __restrict__ cval, float* __restrict__ out, int N)
{
    const int is64 = *flag;
    const long long* batch64 = (const long long*)batch32;
    int i = blockIdx.x * 256 + threadIdx.x;
    if (i < N) {
        int g = is64 ? (int)batch64[i] : batch32[i];
        out[i] = cval[g];
    }
}

extern "C" void kernel_launch(void* const* d_in, const int* in_sizes, int n_in,
                              void* d_out, int out_size, void* d_ws, size_t ws_size,
                              hipStream_t stream)
{
    const float* x   = (const float*)d_in[0];
    const int*   bat = (const int*)d_in[1];
    const float* W1  = (const float*)d_in[2];
    const float* b1  = (const float*)d_in[3];
    const float* W2  = (const float*)d_in[4];
    const float* b2  = (const float*)d_in[5];
    const float* Wc  = (const float*)d_in[6];
    const float* bc  = (const float*)d_in[7];
    float* out = (float*)d_out;
    const int N = in_sizes[0] / D;   // 100000

    float* cval = (float*)d_ws;
    int*   flag = (int*)((char*)d_ws + NUM_GRAPHS * sizeof(float));

    graph_mlp<<<NUM_GRAPHS, 256, 0, stream>>>(x, bat, W1, b1, W2, b2, Wc, bc,
                                              cval, flag, N);
    scatter_out<<<(N + 255) / 256, 256, 0, stream>>>(bat, flag, cval, out, N);
}